// Round 9
// baseline (136.220 us; speedup 1.0000x reference)
//
#include <hip/hip_runtime.h>

// Problem constants (from reference)
#define BB      2
#define CC      256
#define HH      384
#define WW      384
#define N_ACT   16384
#define GRID_N  192                  // index grid; coord = 2*idx (OFFSET=0, STRIDE=2)
#define NCELL   (GRID_N * GRID_N)
#define PLANE_F4 ((HH * WW) / 4)     // 36864 float4 per (b,c) plane
#define ROW_F4   (WW / 4)            // 96 float4 per row
#define PAIRS_PER_PLANE (PLANE_F4 / 2)   // 18432 row-pair float4 slots
#define BLK_PER_PLANE (PAIRS_PER_PLANE / 256)  // 72
#define NXCD    8

// Native clang vector type — required by __builtin_nontemporal_load/store.
typedef float fx4 __attribute__((ext_vector_type(4)));

// --- Kernel 1: winner[cell] = max k writing to that cell (numpy last-wins) --
__global__ void winner_scatter_kernel(const int2* __restrict__ idx,
                                      int* __restrict__ winner) {
    int k = blockIdx.x * blockDim.x + threadIdx.x;
    if (k < N_ACT) {
        int2 p = idx[k];                        // p.x = iy, p.y = ix
        atomicMax(&winner[p.x * GRID_N + p.y], k);
    }
}

// --- Kernel 2: fused copy + patch, XCD-local planes -------------------------
// All 72 blocks of plane p share L%8 == p%8 -> one XCD; plane's 64KB x-slice
// and winner map live in that XCD's L2, so gathers are warm-L2 hits.
// Issue order decouples the odd-row stream from the gather chain:
//   vo load first, ve, then winner -> store vo needs only vmcnt(2) (not the
//   winner/gather chain); even-row store alone pays the dependent latency.
__global__ void scatter_main_kernel(const fx4* __restrict__ orig,
                                    const float* __restrict__ x,
                                    const int* __restrict__ winner,
                                    fx4* __restrict__ out) {
    int L   = blockIdx.x;
    int xcd = L & (NXCD - 1);
    int g   = L >> 3;                             // 0..4607
    int p   = (g / BLK_PER_PLANE) * NXCD + xcd;   // plane 0..511
    int j   = g % BLK_PER_PLANE;                  // block-in-plane 0..71

    int q   = j * 256 + threadIdx.x;              // row-pair slot 0..18431
    int gy  = q / ROW_F4;                         // grid row 0..191
    int col = q - gy * ROW_F4;                    // float4 col 0..95

    int base = p * PLANE_F4 + (gy * 2) * ROW_F4 + col;   // even row slot

    // Odd-row float4 issued FIRST so its store waits only on itself.
    fx4 vo = __builtin_nontemporal_load(&orig[base + ROW_F4]);
    fx4 ve = __builtin_nontemporal_load(&orig[base]);
    const int2* wrow2 = reinterpret_cast<const int2*>(winner + gy * GRID_N);
    int2 w = wrow2[col];                          // cells gx=2col, 2col+1

    __builtin_nontemporal_store(vo, &out[base + ROW_F4]);

    // Per-lane exec-masked gathers (only ~35% of cells active); no wrapper
    // branch: a 64-lane wave covering 128 cells is essentially never
    // all-inactive, so the branch was pure overhead.
    const float* xp = x + p * N_ACT;
    if (w.x >= 0) ve[0] = xp[w.x];
    if (w.y >= 0) ve[2] = xp[w.y];

    __builtin_nontemporal_store(ve, &out[base]);
}

extern "C" void kernel_launch(void* const* d_in, const int* in_sizes, int n_in,
                              void* d_out, int out_size, void* d_ws, size_t ws_size,
                              hipStream_t stream) {
    const float* x    = (const float*)d_in[0];   // [B, C, N_ACT]
    const float* orig = (const float*)d_in[1];   // [B, C, H, W]
    const int*   idx  = (const int*)d_in[2];     // [N_ACT, 2]
    float*       out  = (float*)d_out;           // [B, C, H, W]
    int*         winner = (int*)d_ws;            // NCELL ints = 147456 B

    // 1. winner map = -1 (0xFF bytes) — async memset is graph-capturable
    (void)hipMemsetAsync(winner, 0xFF, NCELL * sizeof(int), stream);
    // 2. last-write-wins via atomicMax over k
    winner_scatter_kernel<<<dim3((N_ACT + 255) / 256), dim3(256), 0, stream>>>(
        (const int2*)idx, winner);
    // 3. fused copy + patch, XCD-local planes
    scatter_main_kernel<<<dim3(BB * CC * BLK_PER_PLANE), dim3(256), 0, stream>>>(
        (const fx4*)orig, x, winner, (fx4*)out);
}